// Round 15
// baseline (102.438 us; speedup 1.0000x reference)
//
#include <hip/hip_runtime.h>

#define BB 128
#define LL 336
#define CC 862
#define PRED 96
#define WIN 12
#define S_IN 28
#define S_OUT 8
#define CT 32
#define RS 340                         // x LDS row stride (dwords), mult of 4 (b128-aligned)
#define NB 2                           // batches per block (async pipeline depth)
#define NTILES ((CC + CT - 1) / CT)    // 27
#define SH 14                          // s per half

#define SQRT12F 3.4641016151377544f

// -Sb(t)/sqrt(12), Sb(t) = 2*sum_{k=1..5} sin(pi*k*t/6)   (exact closed forms)
__device__ const float COEFP[12] = {
    0.0f, -2.1547005383792515f, 0.0f, -0.5773502691896258f,
    0.0f, -0.15470053837925146f, 0.0f, 0.15470053837925146f,
    0.0f,  0.5773502691896258f, 0.0f,  2.1547005383792515f
};

// ---- prep kernels ----

// packed weights: wpk[((p*S_IN + s)*CC + c)*2 + {0,1}] = {wA, wP}[c][p][s]
__global__ void prep_wpk(const float* __restrict__ wA, const float* __restrict__ wP,
                         float* __restrict__ wpk) {
    int i = blockIdx.x * 256 + threadIdx.x;          // i = (p*S_IN + s)*CC + c
    if (i >= S_OUT * S_IN * CC) return;
    int c  = i % CC;
    int ps = i / CC;
    int s  = ps % S_IN;
    int p  = ps / S_IN;
    int src = (c * S_OUT + p) * S_IN + s;
    wpk[2 * i]     = wA[src];
    wpk[2 * i + 1] = wP[src];
}

__global__ void prep_mcoef(const float* __restrict__ wA, float* __restrict__ mcoefT) {
    int i = blockIdx.x * 256 + threadIdx.x;          // [p][c]
    if (i >= S_OUT * CC) return;
    int c = i % CC;
    int p = i / CC;
    float s = 0.f;
    for (int k = 0; k < S_IN; ++k) s += wA[(c * S_OUT + p) * S_IN + k];
    mcoefT[i] = 1.0f - s;
}

__global__ void prep_bias(const float* __restrict__ bA, const float* __restrict__ bP,
                          float* __restrict__ biasv) {
    int i = blockIdx.x * 256 + threadIdx.x;          // [t][p][c]
    if (i >= 12 * S_OUT * CC) return;
    int c = i % CC;
    int tp = i / CC;
    int p = tp % S_OUT;
    int t = tp / S_OUT;
    float v = COEFP[t] * bP[c * S_OUT + p];
    if (t == 0) v += SQRT12F * bA[c * S_OUT + p];
    biasv[i] = v;
}

// ---- fused main kernel ----
// r14 structure (CT=32, 512 thr, s-split) + T14 async staging over NB=2 batches:
// tile k+1's global loads are issued into registers BEFORE tile k's compute,
// so HBM transfer overlaps FMA/LDS work (the r10-r14 plateau = phase-serialized HBM).
// Separate stride-15 reduction buffer (conflict-free; r14's stride-14 was 2-way).

template <bool TRANS>
__global__ __launch_bounds__(512, 4) void fused15(
    const float* __restrict__ x,
    const float* __restrict__ wpk,
    const float* __restrict__ mcoefT, const float* __restrict__ biasv,
    const float* __restrict__ wA_raw, const float* __restrict__ wP_raw,
    const float* __restrict__ bAr, const float* __restrict__ bPr,
    float* __restrict__ out)
{
    __shared__ __align__(16) float sxT[CT * RS];   // 43520 B
    __shared__ float red[256 * 15];                // 15360 B (stride 15: odd -> conflict-free)

    const int bbase = blockIdx.y * NB;
    const int c0  = blockIdx.x * CT;
    const int NC  = min(CT, CC - c0);   // 32 or 30 (always even)
    const int tid = threadIdx.x;        // 0..511

    // staging mapping: slot = float2 column pair, r0 = row within 32-row group
    const int slot = tid & 15;
    const int r0   = tid >> 4;          // 0..31
    const int col  = 2 * slot;
    const int csrc = (col + 1 < NC) ? col : (NC - 2);
    const float* xbase = x + ((size_t)bbase * LL) * CC + c0 + csrc;

    // ---- stage tile 0: regs -> LDS ----
    float2 vbuf[11];
    #pragma unroll
    for (int k = 0; k < 11; ++k) {
        const int r = r0 + 32 * k;
        if (r < LL) vbuf[k] = *reinterpret_cast<const float2*>(xbase + (size_t)r * CC);
    }
    {
        float* d0 = sxT + col * RS;
        float* d1 = sxT + (col + 1) * RS;
        #pragma unroll
        for (int k = 0; k < 11; ++k) {
            const int r = r0 + 32 * k;
            if (r < LL) { d0[r] = vbuf[k].x; d1[r] = vbuf[k].y; }
        }
    }
    __syncthreads();

    const int cc = tid & 31;
    const int p  = (tid >> 5) & 7;
    const int h  = tid >> 8;             // 0 or 1
    const int c  = c0 + cc;
    const bool wrOK = (cc < NC);
    const int cl = wrOK ? c : (CC - 1);  // clamped for global loads
    const int s0 = h * SH;

    #pragma unroll 1
    for (int kb = 0; kb < NB; ++kb) {
        // ---- issue next tile's global loads NOW (latency hides under compute) ----
        if (kb + 1 < NB) {
            const float* xb2 = xbase + (size_t)(kb + 1) * LL * CC;
            #pragma unroll
            for (int k = 0; k < 11; ++k) {
                const int r = r0 + 32 * k;
                if (r < LL) vbuf[k] = *reinterpret_cast<const float2*>(xb2 + (size_t)r * CC);
            }
        }

        // ---- compute from sxT ----
        float A0 = 0.f, A6 = 0.f;
        float Au[5] = {0.f, 0.f, 0.f, 0.f, 0.f};
        float Pv[5] = {0.f, 0.f, 0.f, 0.f, 0.f};
        float msum = 0.f;
        float sw = 0.f;

        const float* xrow = sxT + cc * RS + 12 * s0;

        #pragma unroll 2
        for (int i = 0; i < SH; ++i) {
            const int s = s0 + i;
            float wa, wp;
            if (TRANS) {
                const float2 w = *reinterpret_cast<const float2*>(
                    wpk + 2 * ((size_t)(p * S_IN + s) * CC + cl));
                wa = w.x; wp = w.y;
            } else {
                wa = wA_raw[(size_t)(cl * S_OUT + p) * S_IN + s];
                wp = wP_raw[(size_t)(cl * S_OUT + p) * S_IN + s];
                sw += wa;
            }
            const float4 xa = *reinterpret_cast<const float4*>(xrow + 12 * i);
            const float4 xb = *reinterpret_cast<const float4*>(xrow + 12 * i + 4);
            const float4 xc = *reinterpret_cast<const float4*>(xrow + 12 * i + 8);

            const float u1 = xa.y + xc.w;
            const float u2 = xa.z + xc.z;
            const float u3 = xa.w + xc.y;
            const float u4 = xb.x + xc.x;
            const float u5 = xb.y + xb.w;
            const float v1 = xa.y - xc.w;
            const float v2 = xa.z - xc.z;
            const float v3 = xa.w - xc.y;
            const float v4 = xb.x - xc.x;
            const float v5 = xb.y - xb.w;

            A0 = fmaf(wa, xa.x, A0);
            A6 = fmaf(wa, xb.z, A6);
            Au[0] = fmaf(wa, u1, Au[0]);
            Au[1] = fmaf(wa, u2, Au[1]);
            Au[2] = fmaf(wa, u3, Au[2]);
            Au[3] = fmaf(wa, u4, Au[3]);
            Au[4] = fmaf(wa, u5, Au[4]);
            Pv[0] = fmaf(wp, v1, Pv[0]);
            Pv[1] = fmaf(wp, v2, Pv[1]);
            Pv[2] = fmaf(wp, v3, Pv[2]);
            Pv[3] = fmaf(wp, v4, Pv[3]);
            Pv[4] = fmaf(wp, v5, Pv[4]);

            msum += (xa.x + xb.z) + ((u1 + u2) + (u3 + u4) + u5);
        }

        __syncthreads();                 // everyone done reading sxT

        // ---- overwrite sxT with next tile (regs already loaded/in flight) ----
        if (kb + 1 < NB) {
            float* d0 = sxT + col * RS;
            float* d1 = sxT + (col + 1) * RS;
            #pragma unroll
            for (int k = 0; k < 11; ++k) {
                const int r = r0 + 32 * k;
                if (r < LL) { d0[r] = vbuf[k].x; d1[r] = vbuf[k].y; }
            }
        }

        // ---- half-combine via red (stride 15, conflict-free) ----
        if (h == 1) {
            float* r = red + (p * 32 + cc) * 15;
            r[0] = A0;  r[1] = A6;
            r[2] = Au[0]; r[3] = Au[1]; r[4] = Au[2]; r[5] = Au[3]; r[6] = Au[4];
            r[7] = Pv[0]; r[8] = Pv[1]; r[9] = Pv[2]; r[10] = Pv[3]; r[11] = Pv[4];
            r[12] = msum; r[13] = sw;
        }
        __syncthreads();                 // red ready AND sxT rewritten

        if (h == 0) {
            const float* r = red + (p * 32 + cc) * 15;
            A0 += r[0];  A6 += r[1];
            Au[0] += r[2]; Au[1] += r[3]; Au[2] += r[4]; Au[3] += r[5]; Au[4] += r[6];
            Pv[0] += r[7]; Pv[1] += r[8]; Pv[2] += r[9]; Pv[3] += r[10]; Pv[4] += r[11];
            msum += r[12]; sw += r[13];

            if (wrOK) {
                const float mean = msum * (1.0f / LL);
                float mc, bias[12];
                if (TRANS) {
                    mc = mcoefT[p * CC + c];
                    #pragma unroll
                    for (int t = 0; t < 12; ++t)
                        bias[t] = biasv[(size_t)(t * S_OUT + p) * CC + c];
                } else {
                    mc = 1.0f - sw;
                    const float ba = bAr[c * S_OUT + p], bp = bPr[c * S_OUT + p];
                    #pragma unroll
                    for (int t = 0; t < 12; ++t)
                        bias[t] = COEFP[t] * bp + (t == 0 ? SQRT12F * ba : 0.f);
                }
                const float mb = mean * mc;
                float* ob = out + ((size_t)(bbase + kb) * PRED + p * WIN) * CC + c;
                ob[0]               = A0 + mb + bias[0];
                ob[(size_t)6 * CC]  = A6 + mb + bias[6];
                #pragma unroll
                for (int t = 1; t <= 5; ++t) {
                    ob[(size_t)t * CC]        = 0.5f * (Au[t-1] + Pv[t-1]) + mb + bias[t];
                    ob[(size_t)(12 - t) * CC] = 0.5f * (Au[t-1] - Pv[t-1]) + mb + bias[12 - t];
                }
            }
        }
    }
}

extern "C" void kernel_launch(void* const* d_in, const int* in_sizes, int n_in,
                              void* d_out, int out_size, void* d_ws, size_t ws_size,
                              hipStream_t stream) {
    const float* x  = (const float*)d_in[0];
    const float* wA = (const float*)d_in[1];
    const float* bA = (const float*)d_in[2];
    const float* wP = (const float*)d_in[3];
    const float* bP = (const float*)d_in[4];
    float* out = (float*)d_out;

    const size_t nW  = (size_t)S_OUT * S_IN * CC;    // 193088
    const size_t nM  = (size_t)S_OUT * CC;           // 6896
    const size_t nBv = (size_t)12 * S_OUT * CC;      // 82752
    const size_t need = (2 * nW + nM + nBv) * sizeof(float);

    dim3 grid(NTILES, BB / NB);

    if (ws_size >= need) {
        float* wpk    = (float*)d_ws;                // 2*nW floats
        float* mcoefT = wpk + 2 * nW;
        float* biasv  = mcoefT + nM;

        prep_wpk<<<(int)((nW + 255) / 256), 256, 0, stream>>>(wA, wP, wpk);
        prep_mcoef<<<(int)((nM + 255) / 256), 256, 0, stream>>>(wA, mcoefT);
        prep_bias<<<(int)((nBv + 255) / 256), 256, 0, stream>>>(bA, bP, biasv);

        fused15<true><<<grid, 512, 0, stream>>>(
            x, wpk, mcoefT, biasv,
            nullptr, nullptr, nullptr, nullptr, out);
    } else {
        fused15<false><<<grid, 512, 0, stream>>>(
            x, nullptr, nullptr, nullptr,
            wA, wP, bA, bP, out);
    }
}

// Round 16
// 59.120 us; speedup vs baseline: 1.7327x; 1.7327x over previous
//
#include <hip/hip_runtime.h>

#define BB 128
#define LL 336
#define CC 862
#define PRED 96
#define WIN 12
#define S_IN 28
#define S_OUT 8
#define CT 128
#define NTILES 7                       // ceil(862/128)
#define NCH 14                         // s-chunks of 2 windows
#define LSTR 25                        // LDS per-channel stride (odd -> conflict-free)

#define SQRT12F 3.4641016151377544f

// -Sb(t)/sqrt(12), Sb(t) = 2*sum_{k=1..5} sin(pi*k*t/6)   (exact closed forms)
__device__ const float COEFP[12] = {
    0.0f, -2.1547005383792515f, 0.0f, -0.5773502691896258f,
    0.0f, -0.15470053837925146f, 0.0f, 0.15470053837925146f,
    0.0f,  0.5773502691896258f, 0.0f,  2.1547005383792515f
};

// ---- prep kernels ----

// packed weights: wpk[((p*S_IN + s)*CC + c)*2 + {0,1}] = {wA, wP}[c][p][s]
__global__ void prep_wpk(const float* __restrict__ wA, const float* __restrict__ wP,
                         float* __restrict__ wpk) {
    int i = blockIdx.x * 256 + threadIdx.x;          // i = (p*S_IN + s)*CC + c
    if (i >= S_OUT * S_IN * CC) return;
    int c  = i % CC;
    int ps = i / CC;
    int s  = ps % S_IN;
    int p  = ps / S_IN;
    int src = (c * S_OUT + p) * S_IN + s;
    wpk[2 * i]     = wA[src];
    wpk[2 * i + 1] = wP[src];
}

__global__ void prep_mcoef(const float* __restrict__ wA, float* __restrict__ mcoefT) {
    int i = blockIdx.x * 256 + threadIdx.x;          // [p][c]
    if (i >= S_OUT * CC) return;
    int c = i % CC;
    int p = i / CC;
    float s = 0.f;
    for (int k = 0; k < S_IN; ++k) s += wA[(c * S_OUT + p) * S_IN + k];
    mcoefT[i] = 1.0f - s;
}

__global__ void prep_bias(const float* __restrict__ bA, const float* __restrict__ bP,
                          float* __restrict__ biasv) {
    int i = blockIdx.x * 256 + threadIdx.x;          // [t][p][c]
    if (i >= 12 * S_OUT * CC) return;
    int c = i % CC;
    int tp = i / CC;
    int p = tp % S_OUT;
    int t = tp / S_OUT;
    float v = COEFP[t] * bP[c * S_OUT + p];
    if (t == 0) v += SQRT12F * bA[c * S_OUT + p];
    biasv[i] = v;
}

// ---- fused main kernel ----
// CT=128 -> 512-B contiguous HBM granules (the r10-r15 plateau was 128-B
// granules at 3448-B stride = ~50% DRAM efficiency = the pinned 3 TB/s).
// 512 thr = (cc 0..127, pg 0..3); thread owns p = pg and pg+4 (24 accs, static).
// x staged per 2-window chunk (12.8 KB LDS, odd stride); chunk k+1 reg-prefetch
// issued before compute of chunk k. Mean free (all threads see all windows).

template <bool TRANS>
__global__ __launch_bounds__(512, 4) void fused16(
    const float* __restrict__ x,
    const float* __restrict__ wpk,
    const float* __restrict__ mcoefT, const float* __restrict__ biasv,
    const float* __restrict__ wA_raw, const float* __restrict__ wP_raw,
    const float* __restrict__ bAr, const float* __restrict__ bPr,
    float* __restrict__ out)
{
    __shared__ float sl[CT * LSTR];    // 12800 B

    const int b   = blockIdx.y;
    const int c0  = blockIdx.x * CT;
    const int NC  = min(CT, CC - c0);  // 128 or 94 (even)
    const int tid = threadIdx.x;       // 0..511

    // staging map: one wave = one full 512-B row segment (64 float2)
    const int slot  = tid & 63;
    const int rbase = tid >> 6;        // 0..7
    const int col   = 2 * slot;
    const int csrc  = (col + 1 < NC) ? col : (NC - 2);
    const float* xb = x + ((size_t)b * LL) * CC + c0 + csrc;

    // compute map
    const int cc = tid & 127;
    const int pg = tid >> 7;           // 0..3 -> p = pg, pg+4
    const int c  = c0 + cc;
    const bool act = (cc < NC);
    const int cl = act ? c : (CC - 1);

    // prologue: issue chunk 0 loads (rows 0..23)
    float2 vbuf[3];
    #pragma unroll
    for (int kk = 0; kk < 3; ++kk) {
        const int r = rbase + 8 * kk;
        vbuf[kk] = *reinterpret_cast<const float2*>(xb + (size_t)r * CC);
    }

    float A0[2] = {0.f, 0.f}, A6[2] = {0.f, 0.f};
    float Au[2][5] = {{0.f,0.f,0.f,0.f,0.f},{0.f,0.f,0.f,0.f,0.f}};
    float Pv[2][5] = {{0.f,0.f,0.f,0.f,0.f},{0.f,0.f,0.f,0.f,0.f}};
    float msum = 0.f;
    float sw[2] = {0.f, 0.f};          // fallback only

    const float2* wq = reinterpret_cast<const float2*>(wpk);

    #pragma unroll 1
    for (int k = 0; k < NCH; ++k) {
        __syncthreads();               // previous compute done reading sl
        #pragma unroll
        for (int kk = 0; kk < 3; ++kk) {
            const int r = rbase + 8 * kk;
            sl[col * LSTR + r]       = vbuf[kk].x;
            sl[(col + 1) * LSTR + r] = vbuf[kk].y;
        }
        __syncthreads();               // sl ready

        // prefetch next chunk (overlaps compute below)
        if (k + 1 < NCH) {
            const float* xn = xb + (size_t)(k + 1) * 24 * CC;
            #pragma unroll
            for (int kk = 0; kk < 3; ++kk) {
                const int r = rbase + 8 * kk;
                vbuf[kk] = *reinterpret_cast<const float2*>(xn + (size_t)r * CC);
            }
        }

        // compute the 2 staged windows
        #pragma unroll
        for (int w = 0; w < 2; ++w) {
            const int s = 2 * k + w;
            float x12[12];
            #pragma unroll
            for (int t = 0; t < 12; ++t) x12[t] = sl[cc * LSTR + w * 12 + t];

            const float u1 = x12[1] + x12[11], v1 = x12[1] - x12[11];
            const float u2 = x12[2] + x12[10], v2 = x12[2] - x12[10];
            const float u3 = x12[3] + x12[9],  v3 = x12[3] - x12[9];
            const float u4 = x12[4] + x12[8],  v4 = x12[4] - x12[8];
            const float u5 = x12[5] + x12[7],  v5 = x12[5] - x12[7];
            msum += (x12[0] + x12[6]) + ((u1 + u2) + (u3 + u4) + u5);

            #pragma unroll
            for (int e = 0; e < 2; ++e) {
                const int p = pg + 4 * e;
                float wa, wpv;
                if (TRANS) {
                    const float2 wv = wq[(size_t)(p * S_IN + s) * CC + cl];
                    wa = wv.x; wpv = wv.y;
                } else {
                    wa  = wA_raw[((size_t)cl * S_OUT + p) * S_IN + s];
                    wpv = wP_raw[((size_t)cl * S_OUT + p) * S_IN + s];
                    sw[e] += wa;
                }
                A0[e] = fmaf(wa, x12[0], A0[e]);
                A6[e] = fmaf(wa, x12[6], A6[e]);
                Au[e][0] = fmaf(wa, u1, Au[e][0]);
                Au[e][1] = fmaf(wa, u2, Au[e][1]);
                Au[e][2] = fmaf(wa, u3, Au[e][2]);
                Au[e][3] = fmaf(wa, u4, Au[e][3]);
                Au[e][4] = fmaf(wa, u5, Au[e][4]);
                Pv[e][0] = fmaf(wpv, v1, Pv[e][0]);
                Pv[e][1] = fmaf(wpv, v2, Pv[e][1]);
                Pv[e][2] = fmaf(wpv, v3, Pv[e][2]);
                Pv[e][3] = fmaf(wpv, v4, Pv[e][3]);
                Pv[e][4] = fmaf(wpv, v5, Pv[e][4]);
            }
        }
    }

    if (!act) return;

    const float mean = msum * (1.0f / LL);

    #pragma unroll
    for (int e = 0; e < 2; ++e) {
        const int p = pg + 4 * e;
        float mc, bias[12];
        if (TRANS) {
            mc = mcoefT[p * CC + c];
            #pragma unroll
            for (int t = 0; t < 12; ++t)
                bias[t] = biasv[(size_t)(t * S_OUT + p) * CC + c];
        } else {
            mc = 1.0f - sw[e];
            const float ba = bAr[c * S_OUT + p], bp = bPr[c * S_OUT + p];
            #pragma unroll
            for (int t = 0; t < 12; ++t)
                bias[t] = COEFP[t] * bp + (t == 0 ? SQRT12F * ba : 0.f);
        }
        const float mb = mean * mc;
        float* ob = out + ((size_t)b * PRED + p * WIN) * CC + c;
        ob[0]              = A0[e] + mb + bias[0];
        ob[(size_t)6 * CC] = A6[e] + mb + bias[6];
        #pragma unroll
        for (int t = 1; t <= 5; ++t) {
            ob[(size_t)t * CC]        = 0.5f * (Au[e][t-1] + Pv[e][t-1]) + mb + bias[t];
            ob[(size_t)(12 - t) * CC] = 0.5f * (Au[e][t-1] - Pv[e][t-1]) + mb + bias[12 - t];
        }
    }
}

extern "C" void kernel_launch(void* const* d_in, const int* in_sizes, int n_in,
                              void* d_out, int out_size, void* d_ws, size_t ws_size,
                              hipStream_t stream) {
    const float* x  = (const float*)d_in[0];
    const float* wA = (const float*)d_in[1];
    const float* bA = (const float*)d_in[2];
    const float* wP = (const float*)d_in[3];
    const float* bP = (const float*)d_in[4];
    float* out = (float*)d_out;

    const size_t nW  = (size_t)S_OUT * S_IN * CC;    // 193088
    const size_t nM  = (size_t)S_OUT * CC;           // 6896
    const size_t nBv = (size_t)12 * S_OUT * CC;      // 82752
    const size_t need = (2 * nW + nM + nBv) * sizeof(float);

    dim3 grid(NTILES, BB);

    if (ws_size >= need) {
        float* wpk    = (float*)d_ws;                // 2*nW floats
        float* mcoefT = wpk + 2 * nW;
        float* biasv  = mcoefT + nM;

        prep_wpk<<<(int)((nW + 255) / 256), 256, 0, stream>>>(wA, wP, wpk);
        prep_mcoef<<<(int)((nM + 255) / 256), 256, 0, stream>>>(wA, mcoefT);
        prep_bias<<<(int)((nBv + 255) / 256), 256, 0, stream>>>(bA, bP, biasv);

        fused16<true><<<grid, 512, 0, stream>>>(
            x, wpk, mcoefT, biasv,
            nullptr, nullptr, nullptr, nullptr, out);
    } else {
        fused16<false><<<grid, 512, 0, stream>>>(
            x, nullptr, nullptr, nullptr,
            wA, wP, bA, bP, out);
    }
}